// Round 2
// baseline (158.584 us; speedup 1.0000x reference)
//
#include <hip/hip_runtime.h>
#include <hip/hip_cooperative_groups.h>

namespace cg = cooperative_groups;

// Problem constants (from setup_inputs): B=64, C=4, H=W=256, N=128
constexpr int Bimg = 64;
constexpr int C    = 4;
constexpr int Ww   = 256;
constexpr int Np   = 128;
constexpr int HW   = 256 * 256;

constexpr float PULL_W = 0.25f;
constexpr float PUSH_W = 0.25f;

// Single cooperative kernel: 64 blocks (one per image) x 128 threads (one per
// match point). Phase 1: per-image pull/push partials -> d_ws. grid.sync().
// Phase 2: block 0 reduces the 64 partials and writes the two output scalars.
// No atomics, no init kernel -> one graph node, deterministic result.
__global__ __launch_bounds__(Np) void ae_loss_coop(
        const float* __restrict__ pred,     // (B,C,H,W)
        const float* __restrict__ target,   // (B,C,H,W)
        const int*   __restrict__ match,    // (B,N,2,2)
        float* __restrict__ out,            // [pull_all, push_all]
        float* __restrict__ ws)             // >= 128 floats scratch
{
    const int b = blockIdx.x;
    const int n = threadIdx.x;

    __shared__ float s_sh[Np];
    __shared__ float red_pull[2];
    __shared__ float red_push[2];

    // match[b][n][p][q]: 4 consecutive ints, 16B aligned
    const int4 m = *reinterpret_cast<const int4*>(match + ((size_t)(b * Np + n)) * 4);
    const int tl_off = m.x * Ww + m.y;   // tl_y*W + tl_x
    const int br_off = m.z * Ww + m.w;   // br_y*W + br_x

    const float* pb = pred   + (size_t)b * C * HW;
    const float* tb = target + (size_t)b * C * HW;

    float pull = 0.0f;
    float s    = 0.0f;
#pragma unroll
    for (int c = 0; c < C; ++c) {
        const float tl = pb[c * HW + tl_off];
        const float br = tb[c * HW + br_off];
        const float d  = tl - br;
        pull += d * d;          // (tl-me)^2 + (br-me)^2 = d^2/2, fold 0.5 below
        s    += tl + br;        // 2*me_c, fold 0.5 below
    }
    pull *= 0.5f;
    s    *= 0.5f;

    s_sh[n] = s;
    __syncthreads();

    // push: sum_{j != n} relu(1 - |s_n - s_j|)
    float push = 0.0f;
#pragma unroll 8
    for (int j = 0; j < Np; ++j) {
        const float v = 1.0f - fabsf(s - s_sh[j]);
        if (j != n && v > 0.0f) push += v;
    }

    // wave (64-lane) reduction of pull/push
#pragma unroll
    for (int off = 32; off > 0; off >>= 1) {
        pull += __shfl_down(pull, off, 64);
        push += __shfl_down(push, off, 64);
    }
    const int lane = n & 63;
    const int wv   = n >> 6;          // 2 waves per block
    if (lane == 0) {
        red_pull[wv] = pull;
        red_push[wv] = push;
    }
    __syncthreads();

    if (n == 0) {
        // pre-scale so the final reduce is a plain sum
        const float pull_b = (red_pull[0] + red_pull[1]) * (PULL_W / (float)Np);
        const float push_b = (red_push[0] + red_push[1]) *
                             (PUSH_W / ((float)Np * (float)(Np - 1)));
        // device-scope stores so block 0 (possibly another XCD) sees them
        __hip_atomic_store(&ws[b],        pull_b, __ATOMIC_RELAXED, __HIP_MEMORY_SCOPE_AGENT);
        __hip_atomic_store(&ws[Bimg + b], push_b, __ATOMIC_RELAXED, __HIP_MEMORY_SCOPE_AGENT);
    }

    cg::this_grid().sync();

    if (b == 0) {
        // wave 0 reduces the 64 pull partials, wave 1 the 64 push partials
        float v = __hip_atomic_load(&ws[n], __ATOMIC_RELAXED, __HIP_MEMORY_SCOPE_AGENT);
#pragma unroll
        for (int off = 32; off > 0; off >>= 1)
            v += __shfl_down(v, off, 64);
        if (lane == 0)
            out[wv] = v;   // wave 0 -> out[0]=pull_all, wave 1 -> out[1]=push_all
    }
}

extern "C" void kernel_launch(void* const* d_in, const int* in_sizes, int n_in,
                              void* d_out, int out_size, void* d_ws, size_t ws_size,
                              hipStream_t stream) {
    const float* pred   = (const float*)d_in[0];
    const float* target = (const float*)d_in[1];
    const int*   match  = (const int*)d_in[2];
    float* out = (float*)d_out;
    float* ws  = (float*)d_ws;

    void* args[] = {(void*)&pred, (void*)&target, (void*)&match,
                    (void*)&out, (void*)&ws};
    hipLaunchCooperativeKernel((const void*)ae_loss_coop,
                               dim3(Bimg), dim3(Np), args, 0, stream);
}

// Round 3
// 129.240 us; speedup vs baseline: 1.2270x; 1.2270x over previous
//
#include <hip/hip_runtime.h>

// Problem constants (from setup_inputs): B=64, C=4, H=W=256, N=128
constexpr int Bimg = 64;
constexpr int C    = 4;
constexpr int Ww   = 256;
constexpr int Np   = 128;
constexpr int HW   = 256 * 256;

constexpr float PULL_W = 0.25f;
constexpr float PUSH_W = 0.25f;

// One block per image, one thread per match point.
__global__ __launch_bounds__(Np) void ae_loss_kernel(
        const float* __restrict__ pred,     // (B,C,H,W)
        const float* __restrict__ target,   // (B,C,H,W)
        const int*   __restrict__ match,    // (B,N,2,2)
        float* __restrict__ out)            // [pull_all, push_all]
{
    const int b = blockIdx.x;
    const int n = threadIdx.x;

    __shared__ float s_sh[Np];
    __shared__ float red_pull[2];
    __shared__ float red_push[2];

    // match[b][n][p][q]: 4 consecutive ints, 16B aligned
    const int4 m = *reinterpret_cast<const int4*>(match + ((size_t)(b * Np + n)) * 4);
    const int tl_off = m.x * Ww + m.y;   // tl_y*W + tl_x
    const int br_off = m.z * Ww + m.w;   // br_y*W + br_x

    const float* pb = pred   + (size_t)b * C * HW;
    const float* tb = target + (size_t)b * C * HW;

    float pull = 0.0f;
    float s    = 0.0f;
#pragma unroll
    for (int c = 0; c < C; ++c) {
        const float tl = pb[c * HW + tl_off];
        const float br = tb[c * HW + br_off];
        const float d  = tl - br;
        pull += d * d;          // (tl-me)^2 + (br-me)^2 = d^2/2, fold 0.5 below
        s    += tl + br;        // 2*me_c, fold 0.5 below
    }
    pull *= 0.5f;
    s    *= 0.5f;

    s_sh[n] = s;
    __syncthreads();

    // push: sum_{j != n} relu(1 - |s_n - s_j|)
    float push = 0.0f;
#pragma unroll 8
    for (int j = 0; j < Np; ++j) {
        const float v = 1.0f - fabsf(s - s_sh[j]);
        if (j != n && v > 0.0f) push += v;
    }

    // wave (64-lane) reduction
#pragma unroll
    for (int off = 32; off > 0; off >>= 1) {
        pull += __shfl_down(pull, off, 64);
        push += __shfl_down(push, off, 64);
    }
    const int lane = n & 63;
    const int wv   = n >> 6;          // 2 waves per block
    if (lane == 0) {
        red_pull[wv] = pull;
        red_push[wv] = push;
    }
    __syncthreads();

    if (n == 0) {
        const float pull_b = red_pull[0] + red_pull[1];
        const float push_b = red_push[0] + red_push[1];
        atomicAdd(out + 0, pull_b * (PULL_W / (float)Np));
        atomicAdd(out + 1, push_b * (PUSH_W / ((float)Np * (float)(Np - 1))));
    }
}

extern "C" void kernel_launch(void* const* d_in, const int* in_sizes, int n_in,
                              void* d_out, int out_size, void* d_ws, size_t ws_size,
                              hipStream_t stream) {
    const float* pred   = (const float*)d_in[0];
    const float* target = (const float*)d_in[1];
    const int*   match  = (const int*)d_in[2];
    float* out = (float*)d_out;

    // 8-byte async memset node: zero the two output accumulators.
    hipMemsetAsync(out, 0, 2 * sizeof(float), stream);
    ae_loss_kernel<<<Bimg, Np, 0, stream>>>(pred, target, match, out);
}

// Round 4
// 128.297 us; speedup vs baseline: 1.2361x; 1.0074x over previous
//
#include <hip/hip_runtime.h>

// Problem constants (from setup_inputs): B=64, C=4, H=W=256, N=128
constexpr int Bimg = 64;
constexpr int C    = 4;
constexpr int Ww   = 256;
constexpr int Np   = 128;
constexpr int HW   = 256 * 256;

constexpr float PULL_W = 0.25f;
constexpr float PUSH_W = 0.25f;

// Single-node design: 64 blocks (one per image) x 128 threads (one per match
// point). Each block writes prescaled pull/push partials into d_ws and
// release-stores a sentinel flag (1u != the 0xAA poison pattern). Block 0
// spin-waits on the 64 flags (writers never wait -> deadlock-free under any
// scheduling), reduces the partials, and writes both output scalars.
// No init node, no atomic accumulation -> deterministic.
__global__ __launch_bounds__(Np) void ae_loss_one(
        const float* __restrict__ pred,     // (B,C,H,W)
        const float* __restrict__ target,   // (B,C,H,W)
        const int*   __restrict__ match,    // (B,N,2,2)
        float* __restrict__ out,            // [pull_all, push_all]
        float* __restrict__ ws)             // [0,64): pull, [64,128): push, [128,192): flags
{
    const int b = blockIdx.x;
    const int n = threadIdx.x;

    __shared__ float s_sh[Np];
    __shared__ float red_pull[2];
    __shared__ float red_push[2];

    // match[b][n][p][q]: 4 consecutive ints, 16B aligned
    const int4 m = *reinterpret_cast<const int4*>(match + ((size_t)(b * Np + n)) * 4);
    const int tl_off = m.x * Ww + m.y;   // tl_y*W + tl_x
    const int br_off = m.z * Ww + m.w;   // br_y*W + br_x

    const float* pb = pred   + (size_t)b * C * HW;
    const float* tb = target + (size_t)b * C * HW;

    float pull = 0.0f;
    float s    = 0.0f;
#pragma unroll
    for (int c = 0; c < C; ++c) {
        const float tl = pb[c * HW + tl_off];
        const float br = tb[c * HW + br_off];
        const float d  = tl - br;
        pull += d * d;          // (tl-me)^2 + (br-me)^2 = d^2/2, fold 0.5 below
        s    += tl + br;        // 2*me_c, fold 0.5 below
    }
    pull *= 0.5f;
    s    *= 0.5f;

    s_sh[n] = s;
    __syncthreads();

    // push: sum_{j != n} relu(1 - |s_n - s_j|)
    float push = 0.0f;
#pragma unroll 8
    for (int j = 0; j < Np; ++j) {
        const float v = 1.0f - fabsf(s - s_sh[j]);
        if (j != n && v > 0.0f) push += v;
    }

    // wave (64-lane) reduction
#pragma unroll
    for (int off = 32; off > 0; off >>= 1) {
        pull += __shfl_down(pull, off, 64);
        push += __shfl_down(push, off, 64);
    }
    const int lane = n & 63;
    const int wv   = n >> 6;          // 2 waves per block
    if (lane == 0) {
        red_pull[wv] = pull;
        red_push[wv] = push;
    }
    __syncthreads();

    unsigned int* flags = reinterpret_cast<unsigned int*>(ws + 2 * Bimg);

    if (n == 0) {
        const float pull_b = (red_pull[0] + red_pull[1]) * (PULL_W / (float)Np);
        const float push_b = (red_push[0] + red_push[1]) *
                             (PUSH_W / ((float)Np * (float)(Np - 1)));
        __hip_atomic_store(&ws[b],        pull_b, __ATOMIC_RELAXED, __HIP_MEMORY_SCOPE_AGENT);
        __hip_atomic_store(&ws[Bimg + b], push_b, __ATOMIC_RELAXED, __HIP_MEMORY_SCOPE_AGENT);
        // release: partials visible to any acquirer of the flag
        __hip_atomic_store(&flags[b], 1u, __ATOMIC_RELEASE, __HIP_MEMORY_SCOPE_AGENT);
    }

    if (b == 0) {
        // thread n spins on flag[n&63]; wave 0 reduces pull, wave 1 push
        while (__hip_atomic_load(&flags[lane], __ATOMIC_ACQUIRE,
                                 __HIP_MEMORY_SCOPE_AGENT) != 1u) { }
        float v = __hip_atomic_load(&ws[wv * Bimg + lane], __ATOMIC_RELAXED,
                                    __HIP_MEMORY_SCOPE_AGENT);
#pragma unroll
        for (int off = 32; off > 0; off >>= 1)
            v += __shfl_down(v, off, 64);
        if (lane == 0)
            out[wv] = v;   // wave 0 -> out[0]=pull_all, wave 1 -> out[1]=push_all
    }
}

extern "C" void kernel_launch(void* const* d_in, const int* in_sizes, int n_in,
                              void* d_out, int out_size, void* d_ws, size_t ws_size,
                              hipStream_t stream) {
    const float* pred   = (const float*)d_in[0];
    const float* target = (const float*)d_in[1];
    const int*   match  = (const int*)d_in[2];
    float* out = (float*)d_out;
    float* ws  = (float*)d_ws;

    ae_loss_one<<<Bimg, Np, 0, stream>>>(pred, target, match, out, ws);
}